// Round 5
// baseline (812.131 us; speedup 1.0000x reference)
//
#include <hip/hip_runtime.h>

// HSMM forward, scaled linear recurrence.
// R5: unlock the register file for real. amdgpu_waves_per_eu(2,2) pins the
// allocator's occupancy target at 2 waves/EU -> 256 VGPR budget, so the
// half P-column (float2[64] = 128 VGPR) stays resident instead of spilling
// to scratch (R4: VGPR_Count=112 < 128 proved the spill).
// All-thread state replication (no wave imbalance), padded partials
// (kills R4's 130K bank-conflict cycles), raw lgkmcnt barriers,
// distance-2 H prefetch, pk-FMA matvec.
// ws: H bf16[16][512][11][256]; part f32[11][88][256]; Pexp f32[256][256];
//     logZ[11][256]; lseZ[256]; lt[11][256]; ltmz[11][256].

#define VV 50000
#define ZB 256
#define LB 11
#define BB 16
#define TB 512
#define NCHUNK 88
#define CROWS 569  // ceil(VV/NCHUNK)

typedef float v2f __attribute__((ext_vector_type(2)));
typedef float v4f __attribute__((ext_vector_type(4)));

static __device__ __forceinline__ float bf16u_to_f(unsigned short u) {
  return __uint_as_float(((unsigned int)u) << 16);
}
static __device__ __forceinline__ unsigned short f_to_bf16u(float f) {
  unsigned int b = __float_as_uint(f);
  b += 0x7FFFu + ((b >> 16) & 1u);
  return (unsigned short)(b >> 16);
}
static __device__ __forceinline__ v2f fma2(v2f a, v2f b, v2f c) {
  return __builtin_elementwise_fma(a, b, c);
}

#define BAR() do { asm volatile("s_waitcnt lgkmcnt(0)" ::: "memory"); \
                   __builtin_amdgcn_s_barrier(); } while (0)

// ---- K1: per-chunk sum of exp(emb) over v (no-max: emb ~ N(0,1), safe in f32)
__global__ void k1_sumexp(const float* __restrict__ emb, float* __restrict__ part) {
  const int l = blockIdx.x / NCHUNK;
  const int c = blockIdx.x % NCHUNK;
  const int t = threadIdx.x;           // 512 threads
  const int zi = (t & 63) * 4;
  const int ro = t >> 6;               // 0..7
  const int v0 = c * CROWS;
  const int v1 = (v0 + CROWS < VV) ? (v0 + CROWS) : VV;
  const float* base = emb + (size_t)l * VV * ZB;
  float a0 = 0.f, a1 = 0.f, a2 = 0.f, a3 = 0.f;
  int v = v0 + ro;
  for (; v + 24 < v1; v += 32) {
    float4 x0 = *(const float4*)(base + (size_t)(v)*ZB + zi);
    float4 x1 = *(const float4*)(base + (size_t)(v + 8) * ZB + zi);
    float4 x2 = *(const float4*)(base + (size_t)(v + 16) * ZB + zi);
    float4 x3 = *(const float4*)(base + (size_t)(v + 24) * ZB + zi);
    a0 += __expf(x0.x) + __expf(x1.x) + __expf(x2.x) + __expf(x3.x);
    a1 += __expf(x0.y) + __expf(x1.y) + __expf(x2.y) + __expf(x3.y);
    a2 += __expf(x0.z) + __expf(x1.z) + __expf(x2.z) + __expf(x3.z);
    a3 += __expf(x0.w) + __expf(x1.w) + __expf(x2.w) + __expf(x3.w);
  }
  for (; v < v1; v += 8) {
    float4 x0 = *(const float4*)(base + (size_t)v * ZB + zi);
    a0 += __expf(x0.x); a1 += __expf(x0.y); a2 += __expf(x0.z); a3 += __expf(x0.w);
  }
  __shared__ float red[8][ZB];
  red[ro][zi] = a0; red[ro][zi + 1] = a1; red[ro][zi + 2] = a2; red[ro][zi + 3] = a3;
  __syncthreads();
  if (t < ZB) {
    float s = 0.f;
#pragma unroll
    for (int r = 0; r < 8; ++r) s += red[r][t];
    part[((size_t)l * NCHUNK + c) * ZB + t] = s;
  }
}

// ---- K2: combine partials -> logZ; lse over l of l_per_z; Pexp rows
__global__ void k2_combine(const float* __restrict__ part, const float* __restrict__ zpz,
                           const float* __restrict__ lpz, float* __restrict__ logZ,
                           float* __restrict__ lseZ, float* __restrict__ Pexp) {
  const int bid = blockIdx.x;
  const int t = threadIdx.x;  // 256
  if (bid < LB) {
    float s = 0.f;
    for (int c = 0; c < NCHUNK; ++c) s += part[((size_t)bid * NCHUNK + c) * ZB + t];
    logZ[bid * ZB + t] = __logf(s);
  } else if (bid == LB) {
    float lv[LB]; float m = -1e30f;
#pragma unroll
    for (int l = 0; l < LB; ++l) { lv[l] = lpz[t * LB + l]; m = fmaxf(m, lv[l]); }
    float s = 0.f;
#pragma unroll
    for (int l = 0; l < LB; ++l) s += __expf(lv[l] - m);
    lseZ[t] = m + __logf(s);
  } else {
    const int r = bid - (LB + 1);
    const float x = zpz[r * ZB + t];
    __shared__ float sA[4], sB[4];
    float m = x;
#pragma unroll
    for (int off = 32; off >= 1; off >>= 1) m = fmaxf(m, __shfl_xor(m, off, 64));
    if ((t & 63) == 0) sA[t >> 6] = m;
    __syncthreads();
    m = fmaxf(fmaxf(sA[0], sA[1]), fmaxf(sA[2], sA[3]));
    const float e = __expf(x - m);
    float s = e;
#pragma unroll
    for (int off = 32; off >= 1; off >>= 1) s += __shfl_xor(s, off, 64);
    if ((t & 63) == 0) sB[t >> 6] = s;
    __syncthreads();
    const float tot = sB[0] + sB[1] + sB[2] + sB[3];
    Pexp[r * ZB + t] = e / tot;
  }
}

// ---- K3: small tables lt = exp(l_term), ltmz = l_term - logZ
__global__ void k3_tables(const float* __restrict__ logZ, const float* __restrict__ lseZ,
                          const float* __restrict__ lpz, float* __restrict__ lt,
                          float* __restrict__ ltmz) {
  const int l = blockIdx.x; const int z = threadIdx.x;
  const float ll = lpz[z * LB + l] - lseZ[z];
  lt[l * ZB + z] = __expf(ll);
  ltmz[l * ZB + z] = ll - logZ[l * ZB + z];
}

// ---- K4: build shift-aligned exp-domain emissions H[b][n][l][z] (bf16)
__global__ void k4_build(const int* __restrict__ ng, const float* __restrict__ emb,
                         const float* __restrict__ lt, const float* __restrict__ ltmz,
                         unsigned short* __restrict__ H) {
  const int n = blockIdx.x + 1;
  const int b = blockIdx.y;
  const int z = threadIdx.x;  // 256
  unsigned short* hrow = H + ((size_t)b * TB + n) * LB * ZB + z;
#pragma unroll
  for (int l = 0; l < LB; ++l) {
    const int s = n - 1 - l;
    float h = 0.f;
    if (s >= 0) {
      const int id = ng[((size_t)l * BB + b) * TB + s];
      if (id == 0) h = lt[l * ZB + z];
      else if (id != 1) h = __expf(emb[((size_t)l * VV + id) * ZB + z] + ltmz[l * ZB + z]);
    }
    hrow[(size_t)l * ZB] = f_to_bf16u(h);
  }
}

// ---- K5: the scan. 512 threads/block, one block per batch element.
// thread (q = t>>8, j = t&255): owns P[z][j] for z in [q*128, q*128+128).
// Scan state replicated across both q-halves (identical values).
__global__
__attribute__((amdgpu_flat_work_group_size(512, 512), amdgpu_waves_per_eu(2, 2)))
void k5_forward(const float* __restrict__ Pexp, const unsigned short* __restrict__ H,
                const int* __restrict__ xlen, float* __restrict__ out) {
  const int b = blockIdx.x;
  const int t = threadIdx.x;
  const int q = t >> 8;
  const int j = t & 255;

  __shared__ __align__(16) float S_lds[2][ZB];
  __shared__ float part_pad[2][ZB + 1];
  __shared__ __align__(16) v4f wmaxl[2];
  __shared__ float redm[4];
  __shared__ float red4[4];

  // Half P-column, packed float2, pinned in VGPRs (128 regs).
  v2f Pcol2[64];
#pragma unroll
  for (int c = 0; c < 64; ++c) {
    const int z = q * 128 + 2 * c;
    v2f p; p.x = Pexp[(size_t)z * ZB + j]; p.y = Pexp[(size_t)(z + 1) * ZB + j];
    Pcol2[c] = p;
    asm volatile("" : "+v"(Pcol2[c]));
  }

  // m0 = max_j P[0][j]
  float p0 = Pexp[j];
  float m = p0;
#pragma unroll
  for (int off = 32; off >= 1; off >>= 1) m = fmaxf(m, __shfl_xor(m, off, 64));
  if (q == 0 && (j & 63) == 0) redm[j >> 6] = m;
  if (t == 0) { v4f one = {1.f, 1.f, 1.f, 1.f}; wmaxl[0] = one; wmaxl[1] = one; }
  __syncthreads();
  const float m0 = fmaxf(fmaxf(redm[0], redm[1]), fmaxf(redm[2], redm[3]));

  const int xl = xlen[b];

  // scan state, replicated in all threads (same value for q=0 and q=1)
  float win[LB], wl[LB];
  float C = __logf(m0), cap = 0.f, capC = 0.f, inv = 1.f;
  unsigned short hcA[LB], hcB[LB];
  const unsigned short* hb = H + (size_t)b * TB * LB * ZB + j;

  win[0] = p0 / m0;
  wl[0] = 1.f;
#pragma unroll
  for (int l = 1; l < LB; ++l) { win[l] = 0.f; wl[l] = 0.f; }
#pragma unroll
  for (int l = 0; l < LB; ++l) {
    hcA[l] = hb[((size_t)1 * LB + l) * ZB];
    hcB[l] = hb[((size_t)2 * LB + l) * ZB];
  }

#define BODY(hbuf, n, npre)                                                    \
  do {                                                                         \
    /* phase 1: S[j] (replicated; q==0 publishes) */                           \
    {                                                                          \
      float S = 0.f;                                                           \
      _Pragma("unroll")                                                        \
      for (int l = 0; l < LB; ++l)                                             \
        S = fmaf(wl[l] * bf16u_to_f(hbuf[l]), win[l], S);                      \
      if ((n) == xl) { cap = S; capC = C; }                                    \
      if (q == 0) S_lds[(n) & 1][j] = S;                                       \
    }                                                                          \
    BAR();                                                                     \
    /* phase 2: matvec half-dot (all threads) + prefetch + bookkeeping */      \
    {                                                                          \
      const v4f* Sv = (const v4f*)(&S_lds[(n) & 1][q * 128]);                  \
      v2f a0 = {0.f, 0.f}, a1 = {0.f, 0.f};                                    \
      _Pragma("unroll")                                                        \
      for (int c = 0; c < 32; ++c) {                                           \
        const v4f s = Sv[c];                                                   \
        a0 = fma2(s.lo, Pcol2[2 * c], a0);                                     \
        a1 = fma2(s.hi, Pcol2[2 * c + 1], a1);                                 \
      }                                                                        \
      const v2f at = a0 + a1;                                                  \
      part_pad[q][j] = at.x + at.y;                                            \
    }                                                                          \
    {                                                                          \
      _Pragma("unroll")                                                        \
      for (int l = 0; l < LB; ++l)                                             \
        hbuf[l] = hb[((size_t)(npre)*LB + l) * ZB];                            \
      const v4f wm = wmaxl[((n)-1) & 1];                                       \
      float mx = fmaxf(fmaxf(wm.x, wm.y), fmaxf(wm.z, wm.w));                  \
      mx = fmaxf(mx, 1e-35f);                                                  \
      inv = 1.0f / mx;                                                         \
      const float delta = __logf(mx);                                          \
      float mw = wl[0];                                                        \
      _Pragma("unroll")                                                        \
      for (int l = 1; l < LB - 1; ++l) mw = fmaxf(mw, wl[l]);                  \
      const float a = fmaxf(delta, __logf(fmaxf(mw, 1e-37f)));                 \
      const float es = __expf(-a);                                             \
      _Pragma("unroll")                                                        \
      for (int l = LB - 1; l >= 1; --l) wl[l] = wl[l - 1] * es;                \
      wl[0] = __expf(delta - a);                                               \
      C += a;                                                                  \
    }                                                                          \
    BAR();                                                                     \
    /* phase 3: combine, window push, next stale max */                        \
    {                                                                          \
      const float raw = part_pad[0][j] + part_pad[1][j];                       \
      _Pragma("unroll")                                                        \
      for (int l = LB - 1; l >= 1; --l) win[l] = win[l - 1];                   \
      win[0] = raw * inv;                                                      \
      float wmv = raw;                                                         \
      _Pragma("unroll")                                                        \
      for (int off = 32; off >= 1; off >>= 1)                                  \
        wmv = fmaxf(wmv, __shfl_xor(wmv, off, 64));                            \
      if (q == 0 && (j & 63) == 0) ((float*)&wmaxl[(n) & 1])[j >> 6] = wmv;    \
    }                                                                          \
  } while (0)

  // xl <= 510, so steps 1..510 suffice (255 exact pairs).
  for (int n = 1; n <= 509; n += 2) {
    BODY(hcA, n, n + 2);
    const int npre2 = (n + 3 <= TB - 1) ? (n + 3) : (TB - 1);
    BODY(hcB, n + 1, npre2);
  }
#undef BODY

  // output: out[b] = capC + log(sum_j cap_j); xl==0 -> 0
  float sv = cap;
#pragma unroll
  for (int off = 32; off >= 1; off >>= 1) sv += __shfl_xor(sv, off, 64);
  if (q == 0 && (j & 63) == 0) red4[j >> 6] = sv;
  __syncthreads();
  if (t == 0) {
    const float tot = red4[0] + red4[1] + red4[2] + red4[3];
    out[b] = (xl == 0) ? 0.f : (__logf(tot) + capC);
  }
}

extern "C" void kernel_launch(void* const* d_in, const int* in_sizes, int n_in,
                              void* d_out, int out_size, void* d_ws, size_t ws_size,
                              hipStream_t stream) {
  (void)in_sizes; (void)n_in; (void)out_size; (void)ws_size;
  const int* xlen = (const int*)d_in[1];
  const int* ng = (const int*)d_in[2];
  const float* emb = (const float*)d_in[3];
  const float* zpz = (const float*)d_in[4];
  const float* lpz = (const float*)d_in[5];
  float* out = (float*)d_out;

  char* ws = (char*)d_ws;
  unsigned short* H = (unsigned short*)ws;
  size_t off = (size_t)BB * TB * LB * ZB * 2;
  float* part = (float*)(ws + off); off += (size_t)LB * NCHUNK * ZB * 4;
  float* Pexp = (float*)(ws + off); off += (size_t)ZB * ZB * 4;
  float* logZ = (float*)(ws + off); off += (size_t)LB * ZB * 4;
  float* lseZ = (float*)(ws + off); off += (size_t)ZB * 4;
  float* lt = (float*)(ws + off); off += (size_t)LB * ZB * 4;
  float* ltmz = (float*)(ws + off); off += (size_t)LB * ZB * 4;

  k1_sumexp<<<dim3(LB * NCHUNK), dim3(512), 0, stream>>>(emb, part);
  k2_combine<<<dim3(LB + 1 + ZB), dim3(ZB), 0, stream>>>(part, zpz, lpz, logZ, lseZ, Pexp);
  k3_tables<<<dim3(LB), dim3(ZB), 0, stream>>>(logZ, lseZ, lpz, lt, ltmz);
  k4_build<<<dim3(TB - 1, BB), dim3(ZB), 0, stream>>>(ng, emb, lt, ltmz, H);
  k5_forward<<<dim3(BB), dim3(512), 0, stream>>>(Pexp, H, xlen, out);
}

// Round 6
// 754.308 us; speedup vs baseline: 1.0767x; 1.0767x over previous
//
#include <hip/hip_runtime.h>

// HSMM forward, scaled linear recurrence.
// R6: stop fighting the register allocator (R3/R4/R5: VGPR_Count 164/112/108
// proved the P-column never went register-resident; scratch reloads on the
// matvec chain were the ~2300 cyc/step stall). P now lives in LDS as f16
// (x1024 scale, 128KB dynamic LDS), consumed via v_dot2_f32_f16 with the
// chunked layout that makes every P-read a lane-contiguous ds_read_b128.
// ws: H bf16[16][512][11][256]; part f32[11][64][256]; Pf16T 128KB;
//     Pexp f32[256][256]; logZ[11][256]; lseZ[256]; lt[11][256]; ltmz[11][256].

#define VV 50000
#define ZB 256
#define LB 11
#define BB 16
#define TB 512
#define NCHUNK 64
#define CROWS 782  // ceil(VV/NCHUNK)

typedef float v2f __attribute__((ext_vector_type(2)));
typedef float v4f __attribute__((ext_vector_type(4)));
typedef _Float16 h2 __attribute__((ext_vector_type(2)));
typedef _Float16 h8 __attribute__((ext_vector_type(8)));

static __device__ __forceinline__ float bf16u_to_f(unsigned short u) {
  return __uint_as_float(((unsigned int)u) << 16);
}
static __device__ __forceinline__ unsigned short f_to_bf16u(float f) {
  unsigned int b = __float_as_uint(f);
  b += 0x7FFFu + ((b >> 16) & 1u);
  return (unsigned short)(b >> 16);
}

static __device__ __forceinline__ float dot8(h8 p, h8 s, float acc) {
#if __has_builtin(__builtin_amdgcn_fdot2)
  acc = __builtin_amdgcn_fdot2(p.lo.lo, s.lo.lo, acc, false);
  acc = __builtin_amdgcn_fdot2(p.lo.hi, s.lo.hi, acc, false);
  acc = __builtin_amdgcn_fdot2(p.hi.lo, s.hi.lo, acc, false);
  acc = __builtin_amdgcn_fdot2(p.hi.hi, s.hi.hi, acc, false);
#else
#pragma unroll
  for (int i = 0; i < 8; ++i) acc = fmaf((float)p[i], (float)s[i], acc);
#endif
  return acc;
}

#define BAR() do { asm volatile("s_waitcnt lgkmcnt(0)" ::: "memory"); \
                   __builtin_amdgcn_s_barrier(); } while (0)

// ---- K1: per-chunk sum of exp(emb) over v (no-max: emb ~ N(0,1), safe in f32)
__global__ void k1_sumexp(const float* __restrict__ emb, float* __restrict__ part) {
  const int l = blockIdx.x / NCHUNK;
  const int c = blockIdx.x % NCHUNK;
  const int t = threadIdx.x;           // 512 threads
  const int zi = (t & 63) * 4;
  const int ro = t >> 6;               // 0..7
  const int v0 = c * CROWS;
  const int v1 = (v0 + CROWS < VV) ? (v0 + CROWS) : VV;
  const float* base = emb + (size_t)l * VV * ZB;
  float a0 = 0.f, a1 = 0.f, a2 = 0.f, a3 = 0.f;
  int v = v0 + ro;
  for (; v + 24 < v1; v += 32) {
    float4 x0 = *(const float4*)(base + (size_t)(v)*ZB + zi);
    float4 x1 = *(const float4*)(base + (size_t)(v + 8) * ZB + zi);
    float4 x2 = *(const float4*)(base + (size_t)(v + 16) * ZB + zi);
    float4 x3 = *(const float4*)(base + (size_t)(v + 24) * ZB + zi);
    a0 += __expf(x0.x) + __expf(x1.x) + __expf(x2.x) + __expf(x3.x);
    a1 += __expf(x0.y) + __expf(x1.y) + __expf(x2.y) + __expf(x3.y);
    a2 += __expf(x0.z) + __expf(x1.z) + __expf(x2.z) + __expf(x3.z);
    a3 += __expf(x0.w) + __expf(x1.w) + __expf(x2.w) + __expf(x3.w);
  }
  for (; v < v1; v += 8) {
    float4 x0 = *(const float4*)(base + (size_t)v * ZB + zi);
    a0 += __expf(x0.x); a1 += __expf(x0.y); a2 += __expf(x0.z); a3 += __expf(x0.w);
  }
  __shared__ float red[8][ZB];
  red[ro][zi] = a0; red[ro][zi + 1] = a1; red[ro][zi + 2] = a2; red[ro][zi + 3] = a3;
  __syncthreads();
  if (t < ZB) {
    float s = 0.f;
#pragma unroll
    for (int r = 0; r < 8; ++r) s += red[r][t];
    part[((size_t)l * NCHUNK + c) * ZB + t] = s;
  }
}

// ---- K2: combine partials -> logZ; lse over l of l_per_z; Pexp rows (+f16 x1024)
__global__ void k2_combine(const float* __restrict__ part, const float* __restrict__ zpz,
                           const float* __restrict__ lpz, float* __restrict__ logZ,
                           float* __restrict__ lseZ, float* __restrict__ Pexp,
                           _Float16* __restrict__ Pf16T) {
  const int bid = blockIdx.x;
  const int t = threadIdx.x;  // 256
  if (bid < LB) {
    float s = 0.f;
    for (int c = 0; c < NCHUNK; ++c) s += part[((size_t)bid * NCHUNK + c) * ZB + t];
    logZ[bid * ZB + t] = __logf(s);
  } else if (bid == LB) {
    float lv[LB]; float m = -1e30f;
#pragma unroll
    for (int l = 0; l < LB; ++l) { lv[l] = lpz[t * LB + l]; m = fmaxf(m, lv[l]); }
    float s = 0.f;
#pragma unroll
    for (int l = 0; l < LB; ++l) s += __expf(lv[l] - m);
    lseZ[t] = m + __logf(s);
  } else {
    const int r = bid - (LB + 1);
    const float x = zpz[r * ZB + t];
    __shared__ float sA[4], sB[4];
    float m = x;
#pragma unroll
    for (int off = 32; off >= 1; off >>= 1) m = fmaxf(m, __shfl_xor(m, off, 64));
    if ((t & 63) == 0) sA[t >> 6] = m;
    __syncthreads();
    m = fmaxf(fmaxf(sA[0], sA[1]), fmaxf(sA[2], sA[3]));
    const float e = __expf(x - m);
    float s = e;
#pragma unroll
    for (int off = 32; off >= 1; off >>= 1) s += __shfl_xor(s, off, 64);
    if ((t & 63) == 0) sB[t >> 6] = s;
    __syncthreads();
    const float tot = sB[0] + sB[1] + sB[2] + sB[3];
    const float P = e / tot;
    Pexp[r * ZB + t] = P;
    // chunked transpose for k5's LDS image: slot (r>>3), col t, elem (r&7)
    Pf16T[(size_t)(r >> 3) * 2048 + t * 8 + (r & 7)] = (_Float16)(P * 1024.f);
  }
}

// ---- K3: small tables lt = exp(l_term), ltmz = l_term - logZ
__global__ void k3_tables(const float* __restrict__ logZ, const float* __restrict__ lseZ,
                          const float* __restrict__ lpz, float* __restrict__ lt,
                          float* __restrict__ ltmz) {
  const int l = blockIdx.x; const int z = threadIdx.x;
  const float ll = lpz[z * LB + l] - lseZ[z];
  lt[l * ZB + z] = __expf(ll);
  ltmz[l * ZB + z] = ll - logZ[l * ZB + z];
}

// ---- K4: build shift-aligned exp-domain emissions H[b][n][l][z] (bf16)
__global__ void k4_build(const int* __restrict__ ng, const float* __restrict__ emb,
                         const float* __restrict__ lt, const float* __restrict__ ltmz,
                         unsigned short* __restrict__ H) {
  const int n = blockIdx.x + 1;
  const int b = blockIdx.y;
  const int z = threadIdx.x;  // 256
  unsigned short* hrow = H + ((size_t)b * TB + n) * LB * ZB + z;
#pragma unroll
  for (int l = 0; l < LB; ++l) {
    const int s = n - 1 - l;
    float h = 0.f;
    if (s >= 0) {
      const int id = ng[((size_t)l * BB + b) * TB + s];
      if (id == 0) h = lt[l * ZB + z];
      else if (id != 1) h = __expf(emb[((size_t)l * VV + id) * ZB + z] + ltmz[l * ZB + z]);
    }
    hrow[(size_t)l * ZB] = f_to_bf16u(h);
  }
}

// ---- K5: the scan. 512 threads/block, one block per batch element.
// thread (q = t>>8, j = t&255): computes raw[j] from z-half q.
// P image: 128KB dynamic LDS, f16 x1024, chunked [q][c][j] slots of 8 z.
__global__ __launch_bounds__(512, 1)
void k5_forward(const float* __restrict__ Pexp, const _Float16* __restrict__ Pf16T,
                const unsigned short* __restrict__ H,
                const int* __restrict__ xlen, float* __restrict__ out) {
  const int b = blockIdx.x;
  const int t = threadIdx.x;
  const int q = t >> 8;
  const int j = t & 255;

  extern __shared__ __align__(16) char dynbuf[];  // 128KB: h8 Pl[2*16*256]
  __shared__ __align__(16) h8 S16v[32];           // S as f16[256]
  __shared__ float part_pad[2][ZB + 1];
  __shared__ __align__(16) v4f wmaxl[2];
  __shared__ float redm[4];
  __shared__ float red4[4];

  // fill P image: 128KB global -> LDS, contiguous float4 copy
  {
    const float4* srcv = (const float4*)Pf16T;
    float4* dstv = (float4*)dynbuf;
#pragma unroll
    for (int i = 0; i < 16; ++i) dstv[t + i * 512] = srcv[t + i * 512];
  }

  // m0 = max_j P[0][j]
  const float p0 = Pexp[j];
  float m = p0;
#pragma unroll
  for (int off = 32; off >= 1; off >>= 1) m = fmaxf(m, __shfl_xor(m, off, 64));
  if (q == 0 && (j & 63) == 0) redm[j >> 6] = m;
  if (t == 0) { v4f one = {1.f, 1.f, 1.f, 1.f}; wmaxl[0] = one; wmaxl[1] = one; }
  __syncthreads();
  const float m0 = fmaxf(fmaxf(redm[0], redm[1]), fmaxf(redm[2], redm[3]));

  const int xl = xlen[b];

  // scan state, replicated in all threads (same value for q=0 and q=1)
  float win[LB], wl[LB];
  float C = __logf(m0), cap = 0.f, capC = 0.f, inv = 1.f;
  unsigned short hcA[LB], hcB[LB];
  const unsigned short* hb = H + (size_t)b * TB * LB * ZB + j;

  win[0] = p0 / m0;
  wl[0] = 1.f;
#pragma unroll
  for (int l = 1; l < LB; ++l) { win[l] = 0.f; wl[l] = 0.f; }
#pragma unroll
  for (int l = 0; l < LB; ++l) {
    hcA[l] = hb[((size_t)1 * LB + l) * ZB];
    hcB[l] = hb[((size_t)2 * LB + l) * ZB];
  }

  const h8* Pme = (const h8*)dynbuf + (q * 4096 + j);
  const h8* Sb = S16v + q * 16;

#define BODY(hbuf, n, npre)                                                    \
  do {                                                                         \
    /* phase 1: S[j] (replicated; q==0 publishes as f16) */                    \
    {                                                                          \
      float S = 0.f;                                                           \
      _Pragma("unroll")                                                        \
      for (int l = 0; l < LB; ++l)                                             \
        S = fmaf(wl[l] * bf16u_to_f(hbuf[l]), win[l], S);                      \
      if ((n) == xl) { cap = S; capC = C; }                                    \
      if (q == 0) ((_Float16*)S16v)[j] = (_Float16)S;                          \
    }                                                                          \
    BAR();                                                                     \
    /* phase 2: half-dot via v_dot2_f32_f16 (4 acc chains) */                  \
    {                                                                          \
      float c0 = 0.f, c1 = 0.f, c2 = 0.f, c3 = 0.f;                            \
      _Pragma("unroll")                                                        \
      for (int c = 0; c < 4; ++c) {                                            \
        const h8 pa = Pme[(4 * c + 0) * 256], sa = Sb[4 * c + 0];              \
        const h8 pb = Pme[(4 * c + 1) * 256], sb_ = Sb[4 * c + 1];             \
        const h8 pc = Pme[(4 * c + 2) * 256], sc = Sb[4 * c + 2];              \
        const h8 pd = Pme[(4 * c + 3) * 256], sd = Sb[4 * c + 3];              \
        c0 = dot8(pa, sa, c0);                                                 \
        c1 = dot8(pb, sb_, c1);                                                \
        c2 = dot8(pc, sc, c2);                                                 \
        c3 = dot8(pd, sd, c3);                                                 \
      }                                                                        \
      part_pad[q][j] = (c0 + c1) + (c2 + c3);                                  \
    }                                                                          \
    /* prefetch H + scale bookkeeping (hidden under dot issue) */              \
    {                                                                          \
      _Pragma("unroll")                                                        \
      for (int l = 0; l < LB; ++l)                                             \
        hbuf[l] = hb[((size_t)(npre)*LB + l) * ZB];                            \
      const v4f wm = wmaxl[((n)-1) & 1];                                       \
      float mx = fmaxf(fmaxf(wm.x, wm.y), fmaxf(wm.z, wm.w));                  \
      mx = fmaxf(mx, 1e-35f);                                                  \
      inv = 1.0f / mx;                                                         \
      const float delta = __logf(mx);                                          \
      float mw = wl[0];                                                        \
      _Pragma("unroll")                                                        \
      for (int l = 1; l < LB - 1; ++l) mw = fmaxf(mw, wl[l]);                  \
      const float a = fmaxf(delta, __logf(fmaxf(mw, 1e-37f)));                 \
      const float es = __expf(-a);                                             \
      _Pragma("unroll")                                                        \
      for (int l = LB - 1; l >= 1; --l) wl[l] = wl[l - 1] * es;                \
      wl[0] = __expf(delta - a);                                               \
      C += a;                                                                  \
    }                                                                          \
    BAR();                                                                     \
    /* phase 3: combine (undo x1024), window push, next stale max */           \
    {                                                                          \
      const float raw =                                                        \
          (part_pad[0][j] + part_pad[1][j]) * (1.0f / 1024.0f);                \
      _Pragma("unroll")                                                        \
      for (int l = LB - 1; l >= 1; --l) win[l] = win[l - 1];                   \
      win[0] = raw * inv;                                                      \
      float wmv = raw;                                                         \
      _Pragma("unroll")                                                        \
      for (int off = 32; off >= 1; off >>= 1)                                  \
        wmv = fmaxf(wmv, __shfl_xor(wmv, off, 64));                            \
      if (q == 0 && (j & 63) == 0) ((float*)&wmaxl[(n) & 1])[j >> 6] = wmv;    \
    }                                                                          \
  } while (0)

  // xl <= 510, so steps 1..510 suffice (255 exact pairs).
  for (int n = 1; n <= 509; n += 2) {
    BODY(hcA, n, n + 2);
    const int npre2 = (n + 3 <= TB - 1) ? (n + 3) : (TB - 1);
    BODY(hcB, n + 1, npre2);
  }
#undef BODY

  // output: out[b] = capC + log(sum_j cap_j); xl==0 -> 0
  float sv = cap;
#pragma unroll
  for (int off = 32; off >= 1; off >>= 1) sv += __shfl_xor(sv, off, 64);
  if (q == 0 && (j & 63) == 0) red4[j >> 6] = sv;
  __syncthreads();
  if (t == 0) {
    const float tot = red4[0] + red4[1] + red4[2] + red4[3];
    out[b] = (xl == 0) ? 0.f : (__logf(tot) + capC);
  }
}

extern "C" void kernel_launch(void* const* d_in, const int* in_sizes, int n_in,
                              void* d_out, int out_size, void* d_ws, size_t ws_size,
                              hipStream_t stream) {
  (void)in_sizes; (void)n_in; (void)out_size; (void)ws_size;
  const int* xlen = (const int*)d_in[1];
  const int* ng = (const int*)d_in[2];
  const float* emb = (const float*)d_in[3];
  const float* zpz = (const float*)d_in[4];
  const float* lpz = (const float*)d_in[5];
  float* out = (float*)d_out;

  char* ws = (char*)d_ws;
  unsigned short* H = (unsigned short*)ws;
  size_t off = (size_t)BB * TB * LB * ZB * 2;
  float* part = (float*)(ws + off); off += (size_t)LB * NCHUNK * ZB * 4;
  _Float16* Pf16T = (_Float16*)(ws + off); off += (size_t)2 * 16 * ZB * 8 * 2;
  float* Pexp = (float*)(ws + off); off += (size_t)ZB * ZB * 4;
  float* logZ = (float*)(ws + off); off += (size_t)LB * ZB * 4;
  float* lseZ = (float*)(ws + off); off += (size_t)ZB * 4;
  float* lt = (float*)(ws + off); off += (size_t)LB * ZB * 4;
  float* ltmz = (float*)(ws + off); off += (size_t)LB * ZB * 4;

  // allow 128KB dynamic LDS for k5 (idempotent; no-op if already permitted)
  (void)hipFuncSetAttribute((const void*)k5_forward,
                            hipFuncAttributeMaxDynamicSharedMemorySize, 131072);

  k1_sumexp<<<dim3(LB * NCHUNK), dim3(512), 0, stream>>>(emb, part);
  k2_combine<<<dim3(LB + 1 + ZB), dim3(ZB), 0, stream>>>(part, zpz, lpz, logZ, lseZ,
                                                         Pexp, Pf16T);
  k3_tables<<<dim3(LB), dim3(ZB), 0, stream>>>(logZ, lseZ, lpz, lt, ltmz);
  k4_build<<<dim3(TB - 1, BB), dim3(ZB), 0, stream>>>(ng, emb, lt, ltmz, H);
  k5_forward<<<dim3(BB), dim3(512), 131072, stream>>>(Pexp, Pf16T, H, xlen, out);
}

// Round 7
// 580.621 us; speedup vs baseline: 1.3987x; 1.2991x over previous
//
#include <hip/hip_runtime.h>

// HSMM forward, scaled linear recurrence.
// R7: P never flows through LDS. raw = S*P done by MFMA 16x16x32 bf16 with
// A = S replicated over rows (D rows all equal raw) and B = P fragments
// RESIDENT in VGPRs (loaded once from a pre-swizzled Bimg). Wave-specialized:
// waves 0-3 own the recurrence state, waves 4-7 own 4 j-tiles each (128 frag
// VGPRs). R6's LDS pipe cost (~256 b128/step streaming 128KB of P) drops to
// ~64 light instrs/step.
// ws: H bf16[16][512][11][256]; part f32[11][64][256]; Bimg bf16 128KB;
//     Pexp f32[256][256]; logZ[11][256]; lseZ[256]; lt[11][256]; ltmz[11][256].

#define VV 50000
#define ZB 256
#define LB 11
#define BB 16
#define TB 512
#define NCHUNK 64
#define CROWS 782  // ceil(VV/NCHUNK)

typedef float v4f __attribute__((ext_vector_type(4)));
typedef short bs8 __attribute__((ext_vector_type(8)));

static __device__ __forceinline__ float bf16u_to_f(unsigned short u) {
  return __uint_as_float(((unsigned int)u) << 16);
}
static __device__ __forceinline__ unsigned short f_to_bf16u(float f) {
  unsigned int b = __float_as_uint(f);
  b += 0x7FFFu + ((b >> 16) & 1u);
  return (unsigned short)(b >> 16);
}

#define BAR() do { asm volatile("s_waitcnt lgkmcnt(0)" ::: "memory"); \
                   __builtin_amdgcn_s_barrier(); } while (0)

// ---- K1: per-chunk sum of exp(emb) over v (no-max: emb ~ N(0,1), safe in f32)
__global__ void k1_sumexp(const float* __restrict__ emb, float* __restrict__ part) {
  const int l = blockIdx.x / NCHUNK;
  const int c = blockIdx.x % NCHUNK;
  const int t = threadIdx.x;           // 512 threads
  const int zi = (t & 63) * 4;
  const int ro = t >> 6;               // 0..7
  const int v0 = c * CROWS;
  const int v1 = (v0 + CROWS < VV) ? (v0 + CROWS) : VV;
  const float* base = emb + (size_t)l * VV * ZB;
  float a0 = 0.f, a1 = 0.f, a2 = 0.f, a3 = 0.f;
  int v = v0 + ro;
  for (; v + 24 < v1; v += 32) {
    float4 x0 = *(const float4*)(base + (size_t)(v)*ZB + zi);
    float4 x1 = *(const float4*)(base + (size_t)(v + 8) * ZB + zi);
    float4 x2 = *(const float4*)(base + (size_t)(v + 16) * ZB + zi);
    float4 x3 = *(const float4*)(base + (size_t)(v + 24) * ZB + zi);
    a0 += __expf(x0.x) + __expf(x1.x) + __expf(x2.x) + __expf(x3.x);
    a1 += __expf(x0.y) + __expf(x1.y) + __expf(x2.y) + __expf(x3.y);
    a2 += __expf(x0.z) + __expf(x1.z) + __expf(x2.z) + __expf(x3.z);
    a3 += __expf(x0.w) + __expf(x1.w) + __expf(x2.w) + __expf(x3.w);
  }
  for (; v < v1; v += 8) {
    float4 x0 = *(const float4*)(base + (size_t)v * ZB + zi);
    a0 += __expf(x0.x); a1 += __expf(x0.y); a2 += __expf(x0.z); a3 += __expf(x0.w);
  }
  __shared__ float red[8][ZB];
  red[ro][zi] = a0; red[ro][zi + 1] = a1; red[ro][zi + 2] = a2; red[ro][zi + 3] = a3;
  __syncthreads();
  if (t < ZB) {
    float s = 0.f;
#pragma unroll
    for (int r = 0; r < 8; ++r) s += red[r][t];
    part[((size_t)l * NCHUNK + c) * ZB + t] = s;
  }
}

// ---- K2: combine partials -> logZ; lse over l of l_per_z; Pexp rows + Bimg
__global__ void k2_combine(const float* __restrict__ part, const float* __restrict__ zpz,
                           const float* __restrict__ lpz, float* __restrict__ logZ,
                           float* __restrict__ lseZ, float* __restrict__ Pexp,
                           unsigned short* __restrict__ Bimg) {
  const int bid = blockIdx.x;
  const int t = threadIdx.x;  // 256
  if (bid < LB) {
    float s = 0.f;
    for (int c = 0; c < NCHUNK; ++c) s += part[((size_t)bid * NCHUNK + c) * ZB + t];
    logZ[bid * ZB + t] = __logf(s);
  } else if (bid == LB) {
    float lv[LB]; float m = -1e30f;
#pragma unroll
    for (int l = 0; l < LB; ++l) { lv[l] = lpz[t * LB + l]; m = fmaxf(m, lv[l]); }
    float s = 0.f;
#pragma unroll
    for (int l = 0; l < LB; ++l) s += __expf(lv[l] - m);
    lseZ[t] = m + __logf(s);
  } else {
    const int r = bid - (LB + 1);  // z (row of P)
    const float x = zpz[r * ZB + t];
    __shared__ float sA[4], sB[4];
    float m = x;
#pragma unroll
    for (int off = 32; off >= 1; off >>= 1) m = fmaxf(m, __shfl_xor(m, off, 64));
    if ((t & 63) == 0) sA[t >> 6] = m;
    __syncthreads();
    m = fmaxf(fmaxf(sA[0], sA[1]), fmaxf(sA[2], sA[3]));
    const float e = __expf(x - m);
    float s = e;
#pragma unroll
    for (int off = 32; off >= 1; off >>= 1) s += __shfl_xor(s, off, 64);
    if ((t & 63) == 0) sB[t >> 6] = s;
    __syncthreads();
    const float tot = sB[0] + sB[1] + sB[2] + sB[3];
    const float P = e / tot;
    Pexp[r * ZB + t] = P;
    // B-fragment image for k5: frag(tile, slice), lane = g*16 + col, elem = ii
    // holds B[k = slice*32 + g*8 + ii][col] = P[r][t].
    const int tile = t >> 4, cl = t & 15;
    const int slice = r >> 5, g = (r >> 3) & 3, ii = r & 7;
    Bimg[((size_t)(tile * 8 + slice) * 64 + (g * 16 + cl)) * 8 + ii] = f_to_bf16u(P);
  }
}

// ---- K3: small tables lt = exp(l_term), ltmz = l_term - logZ
__global__ void k3_tables(const float* __restrict__ logZ, const float* __restrict__ lseZ,
                          const float* __restrict__ lpz, float* __restrict__ lt,
                          float* __restrict__ ltmz) {
  const int l = blockIdx.x; const int z = threadIdx.x;
  const float ll = lpz[z * LB + l] - lseZ[z];
  lt[l * ZB + z] = __expf(ll);
  ltmz[l * ZB + z] = ll - logZ[l * ZB + z];
}

// ---- K4: build shift-aligned exp-domain emissions H[b][n][l][z] (bf16)
__global__ void k4_build(const int* __restrict__ ng, const float* __restrict__ emb,
                         const float* __restrict__ lt, const float* __restrict__ ltmz,
                         unsigned short* __restrict__ H) {
  const int n = blockIdx.x + 1;
  const int b = blockIdx.y;
  const int z = threadIdx.x;  // 256
  unsigned short* hrow = H + ((size_t)b * TB + n) * LB * ZB + z;
#pragma unroll
  for (int l = 0; l < LB; ++l) {
    const int s = n - 1 - l;
    float h = 0.f;
    if (s >= 0) {
      const int id = ng[((size_t)l * BB + b) * TB + s];
      if (id == 0) h = lt[l * ZB + z];
      else if (id != 1) h = __expf(emb[((size_t)l * VV + id) * ZB + z] + ltmz[l * ZB + z]);
    }
    hrow[(size_t)l * ZB] = f_to_bf16u(h);
  }
}

// ---- K5: the scan. 512 threads/block, one block per batch element.
// waves 0-3: recurrence state (z = t). waves 4-7: mfma with resident P frags.
__global__ __launch_bounds__(512, 1)
void k5_forward(const float* __restrict__ Pexp, const unsigned short* __restrict__ Bimg,
                const unsigned short* __restrict__ H,
                const int* __restrict__ xlen, float* __restrict__ out) {
  const int b = blockIdx.x;
  const int t = threadIdx.x;
  const int lane = t & 63;

  __shared__ __align__(16) unsigned short S_lds[ZB];  // S as bf16
  __shared__ __align__(16) float raw_lds[ZB];
  __shared__ __align__(16) v4f wmaxl[2];
  __shared__ float redm[4];
  __shared__ float red4[4];

  const int xl = xlen[b];
  float cap = 0.f, capC = 0.f;

  if (t == 0) { v4f one = {1.f, 1.f, 1.f, 1.f}; wmaxl[0] = one; wmaxl[1] = one; }

  float p0 = 0.f;
  if (t < ZB) {
    p0 = Pexp[t];
    float m = p0;
#pragma unroll
    for (int off = 32; off >= 1; off >>= 1) m = fmaxf(m, __shfl_xor(m, off, 64));
    if ((t & 63) == 0) redm[t >> 6] = m;
  }
  __syncthreads();  // barrier #0
  const float m0 = fmaxf(fmaxf(redm[0], redm[1]), fmaxf(redm[2], redm[3]));

  if (t < ZB) {
    // ================= state path (waves 0-3), z = t =================
    float win[LB], wl[LB];
    float C = __logf(m0), inv = 1.f;
    unsigned short hcA[LB], hcB[LB];
    const unsigned short* hb = H + (size_t)b * TB * LB * ZB + t;
    win[0] = p0 / m0;
    wl[0] = 1.f;
#pragma unroll
    for (int l = 1; l < LB; ++l) { win[l] = 0.f; wl[l] = 0.f; }
#pragma unroll
    for (int l = 0; l < LB; ++l) {
      hcA[l] = hb[((size_t)1 * LB + l) * ZB];
      hcB[l] = hb[((size_t)2 * LB + l) * ZB];
    }

#define SBODY(hbuf, n, npre)                                                   \
  do {                                                                         \
    /* P1: S[t] */                                                             \
    {                                                                          \
      float S = 0.f;                                                           \
      _Pragma("unroll")                                                        \
      for (int l = 0; l < LB; ++l)                                             \
        S = fmaf(wl[l] * bf16u_to_f(hbuf[l]), win[l], S);                      \
      if ((n) == xl) { cap = S; capC = C; }                                    \
      S_lds[t] = f_to_bf16u(S);                                                \
    }                                                                          \
    BAR(); /* BAR1: mfma waves read S */                                       \
    /* P2: H prefetch + scale bookkeeping (mfma runs in parallel) */           \
    {                                                                          \
      _Pragma("unroll")                                                        \
      for (int l = 0; l < LB; ++l)                                             \
        hbuf[l] = hb[((size_t)(npre)*LB + l) * ZB];                            \
      const v4f wm = wmaxl[((n)-1) & 1];                                       \
      float mx = fmaxf(fmaxf(wm.x, wm.y), fmaxf(wm.z, wm.w));                  \
      mx = fmaxf(mx, 1e-35f);                                                  \
      inv = 1.0f / mx;                                                         \
      const float delta = __logf(mx);                                          \
      float mw = wl[0];                                                        \
      _Pragma("unroll")                                                        \
      for (int l = 1; l < LB - 1; ++l) mw = fmaxf(mw, wl[l]);                  \
      const float a = fmaxf(delta, __logf(fmaxf(mw, 1e-37f)));                 \
      const float es = __expf(-a);                                             \
      _Pragma("unroll")                                                        \
      for (int l = LB - 1; l >= 1; --l) wl[l] = wl[l - 1] * es;                \
      wl[0] = __expf(delta - a);                                               \
      C += a;                                                                  \
    }                                                                          \
    BAR(); /* BAR2: raw ready */                                               \
    /* P3: consume raw, push window, stale max for n+1 */                      \
    {                                                                          \
      const float raw = raw_lds[t];                                            \
      _Pragma("unroll")                                                        \
      for (int l = LB - 1; l >= 1; --l) win[l] = win[l - 1];                   \
      win[0] = raw * inv;                                                      \
      float wmv = raw;                                                         \
      _Pragma("unroll")                                                        \
      for (int off = 32; off >= 1; off >>= 1)                                  \
        wmv = fmaxf(wmv, __shfl_xor(wmv, off, 64));                            \
      if ((t & 63) == 0) ((float*)&wmaxl[(n) & 1])[t >> 6] = wmv;              \
    }                                                                          \
  } while (0)

    // xl <= 510; steps 1..510 (255 exact pairs).
    for (int n = 1; n <= 509; n += 2) {
      SBODY(hcA, n, n + 2);
      const int np2 = (n + 3 <= TB - 1) ? (n + 3) : (TB - 1);
      SBODY(hcB, n + 1, np2);
    }
#undef SBODY
  } else {
    // ================= mfma path (waves 4-7), 4 j-tiles each =================
    const int w4 = (t >> 6) - 4;
    bs8 frag[4][8];
#pragma unroll
    for (int tt = 0; tt < 4; ++tt)
#pragma unroll
      for (int s = 0; s < 8; ++s) {
        frag[tt][s] = *((const bs8*)Bimg + (size_t)((w4 * 4 + tt) * 8 + s) * 64 + lane);
        asm volatile("" : "+v"(frag[tt][s]));
      }
    const bs8* aptr = (const bs8*)((const char*)S_lds + ((lane >> 4) << 4));
    for (int n = 1; n <= 510; ++n) {
      BAR();  // BAR1: S_lds ready
      bs8 ar[8];
#pragma unroll
      for (int s = 0; s < 8; ++s) ar[s] = aptr[s * 4];  // A = S replicated rows
      v4f acc[4];
#pragma unroll
      for (int tt = 0; tt < 4; ++tt) {
        v4f a = {0.f, 0.f, 0.f, 0.f};
#pragma unroll
        for (int s = 0; s < 8; ++s)
          a = __builtin_amdgcn_mfma_f32_16x16x32_bf16(ar[s], frag[tt][s], a, 0, 0, 0);
        acc[tt] = a;
      }
      if (lane < 16) {
#pragma unroll
        for (int tt = 0; tt < 4; ++tt)
          raw_lds[(w4 * 4 + tt) * 16 + lane] = acc[tt][0];  // D row 0, col=lane
      }
      BAR();  // BAR2: raw published
    }
  }

  // epilogue: out[b] = capC + log(sum_z cap_z); xl==0 -> 0
  if (t < ZB) {
    float sv = cap;
#pragma unroll
    for (int off = 32; off >= 1; off >>= 1) sv += __shfl_xor(sv, off, 64);
    if ((t & 63) == 0) red4[t >> 6] = sv;
  }
  __syncthreads();
  if (t == 0) {
    const float tot = red4[0] + red4[1] + red4[2] + red4[3];
    out[b] = (xl == 0) ? 0.f : (__logf(tot) + capC);
  }
}

extern "C" void kernel_launch(void* const* d_in, const int* in_sizes, int n_in,
                              void* d_out, int out_size, void* d_ws, size_t ws_size,
                              hipStream_t stream) {
  (void)in_sizes; (void)n_in; (void)out_size; (void)ws_size;
  const int* xlen = (const int*)d_in[1];
  const int* ng = (const int*)d_in[2];
  const float* emb = (const float*)d_in[3];
  const float* zpz = (const float*)d_in[4];
  const float* lpz = (const float*)d_in[5];
  float* out = (float*)d_out;

  char* ws = (char*)d_ws;
  unsigned short* H = (unsigned short*)ws;
  size_t off = (size_t)BB * TB * LB * ZB * 2;
  float* part = (float*)(ws + off); off += (size_t)LB * NCHUNK * ZB * 4;
  unsigned short* Bimg = (unsigned short*)(ws + off); off += (size_t)16 * 8 * 64 * 8 * 2;
  float* Pexp = (float*)(ws + off); off += (size_t)ZB * ZB * 4;
  float* logZ = (float*)(ws + off); off += (size_t)LB * ZB * 4;
  float* lseZ = (float*)(ws + off); off += (size_t)ZB * 4;
  float* lt = (float*)(ws + off); off += (size_t)LB * ZB * 4;
  float* ltmz = (float*)(ws + off); off += (size_t)LB * ZB * 4;

  k1_sumexp<<<dim3(LB * NCHUNK), dim3(512), 0, stream>>>(emb, part);
  k2_combine<<<dim3(LB + 1 + ZB), dim3(ZB), 0, stream>>>(part, zpz, lpz, logZ, lseZ,
                                                         Pexp, Bimg);
  k3_tables<<<dim3(LB), dim3(ZB), 0, stream>>>(logZ, lseZ, lpz, lt, ltmz);
  k4_build<<<dim3(TB - 1, BB), dim3(ZB), 0, stream>>>(ng, emb, lt, ltmz, H);
  k5_forward<<<dim3(BB), dim3(512), 0, stream>>>(Pexp, Bimg, H, xlen, out);
}